// Round 9
// baseline (220.773 us; speedup 1.0000x reference)
//
#include <hip/hip_runtime.h>
#include <hip/hip_bf16.h>
#include <cstdint>

// ---------------------------------------------------------------------------
// HierDSFeedForward: LN -> shared SwiGLU FFN + hierarchical top-2 MoE
// S=8192 tokens, C=512, H=1024, G=2 groups x EG=4 experts, K=2
// R17: R16's LDS swizzle zeroed SQ_LDS_BANK_CONFLICT but REGRESSED gemm1
//      51->66us: the source-side column permute makes staged-row lane
//      addresses non-monotone, splitting 64B staging requests (same HBM
//      bytes, ~4x L2 request count). With gload_lds's forced-linear dest,
//      any row-dependent chunk permute breaks monotonicity => the 8-way
//      read conflict (~10%) is the cheaper structural cost. Revert both
//      GEMMs to R15's exact schedule; keep ln_gate float (R16's other
//      change) to cleanly attribute this round's total.
// ---------------------------------------------------------------------------

typedef __bf16 bf16x8 __attribute__((ext_vector_type(8)));
typedef __bf16 bf16x4 __attribute__((ext_vector_type(4)));
typedef float  f32x4  __attribute__((ext_vector_type(4)));

#define S_TOT 8192
#define C_DIM 512
#define H_DIM 1024
// max expert M-tiles at 256 rows: 16384/256 + 8 = 72
#define MAX_ET2 72

__device__ __forceinline__ void gload_lds16(const void* g, void* l) {
  __builtin_amdgcn_global_load_lds(
      (__attribute__((address_space(1))) void*)(void*)(g),
      (__attribute__((address_space(3))) void*)(l),
      16, 0, 0);
}

// panel base (elements): [par][half][panel] of 128x32 bf16 panels
#define PNL(par, h, p) ((((par) * 2 + (h)) * 2 + (p)) * 4096)

#define WAITL do { asm volatile("s_waitcnt lgkmcnt(0)" ::: "memory");          \
                   __builtin_amdgcn_sched_barrier(0); } while (0)
#define BAR __builtin_amdgcn_s_barrier()
#define WVM4 asm volatile("s_waitcnt vmcnt(4)" ::: "memory")
#define WVM0 asm volatile("s_waitcnt vmcnt(0)" ::: "memory")

// ---------------------------------------------------------------------------
__global__ __launch_bounds__(256) void cvt_fused(
    const float* __restrict__ siw, const float* __restrict__ eiw,
    const float* __restrict__ eow, const float* __restrict__ sow,
    __bf16* __restrict__ w1, __bf16* __restrict__ w2) {
  const int i = (blockIdx.x * 256 + threadIdx.x) * 4;
  const float* src;
  __bf16* dst;
  if (i < 2097152) {
    src = (i < 1048576) ? (siw + i) : (eiw + (i - 1048576));
    dst = w1 + i;
  } else {
    const int j = i - 2097152;
    src = (j < 4194304) ? (eow + j) : (sow + (j - 4194304));
    dst = w2 + j;
  }
  float4 v = *(const float4*)src;
  bf16x4 o;
  o[0] = (__bf16)v.x; o[1] = (__bf16)v.y; o[2] = (__bf16)v.z; o[3] = (__bf16)v.w;
  *(bf16x4*)dst = o;
}

// ---------------------------------------------------------------------------
// Wave-per-token LN + gating (float gating); block 0 zeroes cnt[8]+done.
__global__ __launch_bounds__(256) void ln_gate_wave(
    const float* __restrict__ x,
    const float* __restrict__ ln_scale, const float* __restrict__ ln_bias,
    const float* __restrict__ ggw, const float* __restrict__ egw,
    const float* __restrict__ gb, const float* __restrict__ eb,
    __bf16* __restrict__ lnb, float* __restrict__ comb,
    int* __restrict__ cntz)
{
  if (blockIdx.x == 0 && threadIdx.x < 9) cntz[threadIdx.x] = 0;  // cnt[8]+done

  const int wave = threadIdx.x >> 6, lane = threadIdx.x & 63;
  const int s = blockIdx.x * 4 + wave;
  const size_t rowb = (size_t)s * C_DIM;
  const int c0 = lane * 8;

  const float4 va = *(const float4*)(x + rowb + c0);
  const float4 vb = *(const float4*)(x + rowb + c0 + 4);
  float v[8] = {va.x, va.y, va.z, va.w, vb.x, vb.y, vb.z, vb.w};

  float sum = 0.f;
#pragma unroll
  for (int j = 0; j < 8; j++) sum += v[j];
#pragma unroll
  for (int o = 1; o < 64; o <<= 1) sum += __shfl_xor(sum, o, 64);
  const float mu = sum * (1.0f / 512.0f);

  float sq = 0.f;
#pragma unroll
  for (int j = 0; j < 8; j++) { const float d = v[j] - mu; sq += d * d; }
#pragma unroll
  for (int o = 1; o < 64; o <<= 1) sq += __shfl_xor(sq, o, 64);
  const float rs = rsqrtf(sq * (1.0f / 512.0f) + 1e-5f);

  const float4 sa = *(const float4*)(ln_scale + c0);
  const float4 sb = *(const float4*)(ln_scale + c0 + 4);
  const float4 ba = *(const float4*)(ln_bias + c0);
  const float4 bb = *(const float4*)(ln_bias + c0 + 4);
  const float sc[8] = {sa.x, sa.y, sa.z, sa.w, sb.x, sb.y, sb.z, sb.w};
  const float bi[8] = {ba.x, ba.y, ba.z, ba.w, bb.x, bb.y, bb.z, bb.w};

  float y[8];
  bf16x8 yb;
#pragma unroll
  for (int j = 0; j < 8; j++) {
    y[j] = (v[j] - mu) * rs * sc[j] + bi[j];
    yb[j] = (__bf16)y[j];
  }
  *(bf16x8*)(lnb + rowb + c0) = yb;

  float lg[10];
#pragma unroll
  for (int r = 0; r < 10; r++) {
    const float* W = (r < 2) ? (ggw + r * C_DIM + c0) : (egw + (r - 2) * C_DIM + c0);
    const float4 wa = *(const float4*)(W);
    const float4 wb = *(const float4*)(W + 4);
    const float w[8] = {wa.x, wa.y, wa.z, wa.w, wb.x, wb.y, wb.z, wb.w};
    float p = 0.0f;
#pragma unroll
    for (int j = 0; j < 8; j++) p = fmaf(y[j], w[j], p);
    lg[r] = p;
  }
#pragma unroll
  for (int o = 1; o < 64; o <<= 1) {
#pragma unroll
    for (int r = 0; r < 10; r++) lg[r] += __shfl_xor(lg[r], o, 64);
  }

  const float g0 = lg[0] + gb[0], g1 = lg[1] + gb[1];
  const int g = (g1 > g0) ? 1 : 0;
  float el[4], mx = -1e30f;
#pragma unroll
  for (int j = 0; j < 4; j++) {
    el[j] = lg[2 + g * 4 + j] + eb[g * 4 + j];
    mx = fmaxf(mx, el[j]);
  }
  float pr[4], ps = 0.0f;
#pragma unroll
  for (int j = 0; j < 4; j++) { pr[j] = __expf(el[j] - mx); ps += pr[j]; }
  int i0 = 0;
#pragma unroll
  for (int j = 1; j < 4; j++) if (pr[j] > pr[i0]) i0 = j;
  int i1 = -1;
#pragma unroll
  for (int j = 0; j < 4; j++) {
    if (j == i0) continue;
    if (i1 < 0 || pr[j] > pr[i1]) i1 = j;
  }
  const float p0 = pr[i0] / ps, p1 = pr[i1] / ps;
  const float nrm = p0 + p1 + 1e-8f;
  const int e0 = g * 4 + i0, e1 = g * 4 + i1;
  const float w0 = p0 / nrm;
  const float w1v = fmaxf(p1 / nrm, 1e-30f);  // e1 always dispatched (bias)

  if (lane < 8)
    comb[(size_t)s * 8 + lane] = (lane == e0) ? w0 : ((lane == e1) ? w1v : 0.0f);
}

// ---------------------------------------------------------------------------
// Expert-list build + slot map + fused prefix (256-row tiles).
__global__ __launch_bounds__(256) void build_lists(
    const float* __restrict__ comb, int* __restrict__ cnt,
    int* __restrict__ tok, int2* __restrict__ sm,
    int* __restrict__ done, int* __restrict__ off, int* __restrict__ toff) {
  __shared__ int lcnt[8], lbase[8];
  const int t = threadIdx.x;
  if (t < 8) lcnt[t] = 0;
  __syncthreads();
  const int s = blockIdx.x * 256 + t;
  const float* cr = comb + (size_t)s * 8;
  int e0 = -1, e1 = -1;
#pragma unroll
  for (int j = 0; j < 8; j++) {
    if (cr[j] != 0.0f) { if (e0 < 0) e0 = j; else e1 = j; }
  }
  const int l0 = atomicAdd(&lcnt[e0], 1);
  const int l1 = (e1 >= 0) ? atomicAdd(&lcnt[e1], 1) : 0;
  __syncthreads();
  if (t < 8) lbase[t] = atomicAdd(&cnt[t], lcnt[t]);
  __syncthreads();
  const int p0 = lbase[e0] + l0;
  tok[e0 * S_TOT + p0] = s;
  int smy = -1;
  if (e1 >= 0) {
    const int p1 = lbase[e1] + l1;
    tok[e1 * S_TOT + p1] = s;
    smy = (e1 << 16) | p1;
  }
  sm[s] = make_int2((e0 << 16) | p0, smy);

  __syncthreads();
  if (t == 0) {
    __threadfence();
    if (atomicAdd(done, 1) == (int)gridDim.x - 1) {
      __threadfence();
      int sacc = 0, ts = 0;
#pragma unroll
      for (int e = 0; e < 8; e++) {
        const int c = atomicAdd(&cnt[e], 0);
        off[e] = sacc;  sacc += (c + 255) >> 8;
        toff[e] = ts;   ts += c;
      }
      off[8] = sacc; toff[8] = ts;
    }
  }
}

// ---------------------------------------------------------------------------
// GEMM1 + fused SwiGLU, race-free 4-phase/K-tile, 256x(128h) tile.
__global__ __launch_bounds__(512, 1) void gemm1_swiglu(
    const __bf16* __restrict__ A,
    const __bf16* __restrict__ W1,
    __bf16* __restrict__ H)
{
  constexpr int K = C_DIM;    // 512
  constexpr int NT = K / 64;  // 8 K-tiles
  __shared__ __bf16 As[8 * 4096];   // 64 KB
  __shared__ __bf16 Bs[8 * 4096];   // 64 KB (half0=gate, half1=up)

  const int m0  = blockIdx.x * 256;
  const int hc0 = blockIdx.y * 128;
  const int garow0 = hc0 + (hc0 < 1024 ? 0 : 1024);

  const int tid = threadIdx.x, wave = tid >> 6, lane = tid & 63;
  const int wm = wave >> 2, wn = wave & 3;
  const int fm = lane & 15, fq = (lane >> 4) * 8;
  const int srow = wave * 16 + (lane >> 2);
  const int scol = (lane & 3) * 8;
  const int woff = wave * 512;

  const __bf16* aR0 = A  + (size_t)(m0 + srow) * K + scol;
  const __bf16* aR1 = A  + (size_t)(m0 + 128 + srow) * K + scol;
  const __bf16* bR0 = W1 + (size_t)(garow0 + srow) * K + scol;
  const __bf16* bR1 = W1 + (size_t)(garow0 + 1024 + srow) * K + scol;

  f32x4 accg[8][2] = {};
  f32x4 accu[8][2] = {};

#define G1_LD_A0(kb, par) do {                                  \
    gload_lds16(aR0 + (kb), As + PNL(par, 0, 0) + woff);        \
    gload_lds16(aR1 + (kb), As + PNL(par, 1, 0) + woff); } while (0)
#define G1_LD_B0(kb, par) do {                                  \
    gload_lds16(bR0 + (kb), Bs + PNL(par, 0, 0) + woff);        \
    gload_lds16(bR1 + (kb), Bs + PNL(par, 1, 0) + woff); } while (0)
#define G1_LD_A1(kb, par) do {                                  \
    gload_lds16(aR0 + (kb) + 32, As + PNL(par, 0, 1) + woff);   \
    gload_lds16(aR1 + (kb) + 32, As + PNL(par, 1, 1) + woff); } while (0)
#define G1_LD_B1(kb, par) do {                                  \
    gload_lds16(bR0 + (kb) + 32, Bs + PNL(par, 0, 1) + woff);   \
    gload_lds16(bR1 + (kb) + 32, Bs + PNL(par, 1, 1) + woff); } while (0)

#define G1_RDB(par, kc) do {                                                   \
    bg[0] = *(const bf16x8*)&Bs[PNL(par, 0, kc) + (wn * 32 + fm) * 32 + fq];   \
    bg[1] = *(const bf16x8*)&Bs[PNL(par, 0, kc) + (wn * 32 + 16 + fm) * 32 + fq];\
    bu[0] = *(const bf16x8*)&Bs[PNL(par, 1, kc) + (wn * 32 + fm) * 32 + fq];   \
    bu[1] = *(const bf16x8*)&Bs[PNL(par, 1, kc) + (wn * 32 + 16 + fm) * 32 + fq];\
  } while (0)

#define G1_RDA(par, mq, kc) do {                                               \
    _Pragma("unroll")                                                          \
    for (int mi = 0; mi < 4; mi++)                                             \
      af[mi] = *(const bf16x8*)&As[PNL(par, wm, kc) +                          \
                                   ((mq) * 64 + mi * 16 + fm) * 32 + fq];      \
  } while (0)

#define G1_MFMA(mq) do {                                                       \
    __builtin_amdgcn_s_setprio(1);                                             \
    _Pragma("unroll")                                                          \
    for (int mi = 0; mi < 4; mi++) {                                           \
      _Pragma("unroll")                                                        \
      for (int ni = 0; ni < 2; ni++) {                                         \
        accg[(mq) * 4 + mi][ni] = __builtin_amdgcn_mfma_f32_16x16x32_bf16(     \
            af[mi], bg[ni], accg[(mq) * 4 + mi][ni], 0, 0, 0);                 \
        accu[(mq) * 4 + mi][ni] = __builtin_amdgcn_mfma_f32_16x16x32_bf16(     \
            af[mi], bu[ni], accu[(mq) * 4 + mi][ni], 0, 0, 0);                 \
      }                                                                        \
    }                                                                          \
    __builtin_amdgcn_s_setprio(0);                                             \
  } while (0)

  // prologue: tile 0 (kc order); vmcnt(4)+BAR => kc0 readable pre-barrier
  G1_LD_A0(0, 0); G1_LD_B0(0, 0); G1_LD_A1(0, 0); G1_LD_B1(0, 0);
  WVM4;
  BAR;

  int par = 0;
#pragma unroll 1
  for (int t = 0; t < NT; ++t) {
    const bool nxt = (t + 1 < NT);
    const int kb = (t + 1) * 64;
    bf16x8 af[4], bg[2], bu[2];
    // ph0: kc0 mq0 (ready via prev ph3's vmcnt(4)+BAR)
    G1_RDB(par, 0); G1_RDA(par, 0, 0);
    if (nxt) G1_LD_A0(kb, par ^ 1);
    BAR; WAITL; G1_MFMA(0); BAR;
    // ph1: kc0 mq1; tail vmcnt makes kc1 ready across waves after BAR
    G1_RDA(par, 1, 0);
    if (nxt) { G1_LD_B0(kb, par ^ 1); WVM4; } else { WVM0; }
    BAR; WAITL; G1_MFMA(1); BAR;
    // ph2: kc1 mq0
    G1_RDB(par, 1); G1_RDA(par, 0, 1);
    if (nxt) G1_LD_A1(kb, par ^ 1);
    BAR; WAITL; G1_MFMA(0); BAR;
    // ph3: kc1 mq1; tail vmcnt makes next tile's kc0 ready after BAR
    G1_RDA(par, 1, 1);
    if (nxt) { G1_LD_B1(kb, par ^ 1); WVM4; }
    BAR; WAITL; G1_MFMA(1); BAR;
    par ^= 1;
  }
#undef G1_LD_A0
#undef G1_LD_B0
#undef G1_LD_A1
#undef G1_LD_B1
#undef G1_RDB
#undef G1_RDA
#undef G1_MFMA

#pragma unroll
  for (int mg = 0; mg < 8; mg++) {
    const int row0 = m0 + wm * 128 + mg * 16 + ((lane >> 4) << 2);
#pragma unroll
    for (int ni = 0; ni < 2; ni++) {
      const int c = hc0 + wn * 32 + ni * 16 + fm;
#pragma unroll
      for (int r = 0; r < 4; r++) {
        const float a = accg[mg][ni][r];
        const float b = accu[mg][ni][r];
        const float sv = a / (1.0f + __expf(-a));
        H[(size_t)(row0 + r) * (2 * H_DIM) + c] = (__bf16)(sv * b);
      }
    }
  }
}

// ---------------------------------------------------------------------------
// Unified GEMM2, race-free 4-phase/K-tile, 256x256 tile, gathered A.
__global__ __launch_bounds__(512, 1) void gemm2_moe(
    const __bf16* __restrict__ Hb,   // [8192, 2048]
    const __bf16* __restrict__ W2,   // [9, 512, 1024]
    const float* __restrict__ comb,  // [8192, 8]
    const int* __restrict__ cnt,     // [8]
    const int* __restrict__ tok,     // [8, 8192]
    const int* __restrict__ off,     // [9] tile prefix (256-row tiles)
    const int* __restrict__ toff,    // [9] token prefix
    __bf16* __restrict__ Eo,         // [24576, 512]
    float* __restrict__ out,         // fallback only
    int compact)
{
  constexpr int K = H_DIM;    // 1024
  constexpr int NT = K / 64;  // 16 K-tiles
  __shared__ __bf16 As[8 * 4096];
  __shared__ __bf16 Bs[8 * 4096];
  __shared__ int tokLDS[256];

  const int g = blockIdx.x;
  const int T = off[8];
  int e, m0;
  if (g < T) {
    e = 0;
    while (e < 7 && g >= off[e + 1]) e++;
    m0 = (g - off[e]) * 256;
  } else if (g < T + 32) {
    e = 8;
    m0 = (g - T) * 256;
  } else {
    return;
  }
  const int cnt_e = (e == 8) ? S_TOT : cnt[e];
  const int n0 = blockIdx.y * 256;
  const __bf16* Bw = W2 + (size_t)e * C_DIM * H_DIM;
  const int abase = (e == 8) ? 0 : H_DIM;

  const int tid = threadIdx.x, wave = tid >> 6, lane = tid & 63;
  const int wm = wave >> 2, wn = wave & 3;
  const int fm = lane & 15, fq = (lane >> 4) * 8;
  const int srow = wave * 16 + (lane >> 2);
  const int scol = (lane & 3) * 8;
  const int woff = wave * 512;

  if (tid < 256) {
    const int r = m0 + tid;
    tokLDS[tid] = (e == 8) ? r : ((r < cnt_e) ? tok[e * S_TOT + r] : -1);
  }
  __syncthreads();   // tokLDS visible; vmcnt clean before pipelined loop

  int tk0 = tokLDS[srow];       if (tk0 < 0) tk0 = 0;
  int tk1 = tokLDS[128 + srow]; if (tk1 < 0) tk1 = 0;
  const __bf16* aR0 = Hb + abase + (size_t)tk0 * (2 * H_DIM) + scol;
  const __bf16* aR1 = Hb + abase + (size_t)tk1 * (2 * H_DIM) + scol;
  const __bf16* bR0 = Bw + (size_t)(n0 + srow) * K + scol;
  const __bf16* bR1 = Bw + (size_t)(n0 + 128 + srow) * K + scol;

  f32x4 acc[8][4] = {};

#define G2_LD_A0(kb, par) do {                                  \
    gload_lds16(aR0 + (kb), As + PNL(par, 0, 0) + woff);        \
    gload_lds16(aR1 + (kb), As + PNL(par, 1, 0) + woff); } while (0)
#define G2_LD_B0(kb, par) do {                                  \
    gload_lds16(bR0 + (kb), Bs + PNL(par, 0, 0) + woff);        \
    gload_lds16(bR1 + (kb), Bs + PNL(par, 1, 0) + woff); } while (0)
#define G2_LD_A1(kb, par) do {                                  \
    gload_lds16(aR0 + (kb) + 32, As + PNL(par, 0, 1) + woff);   \
    gload_lds16(aR1 + (kb) + 32, As + PNL(par, 1, 1) + woff); } while (0)
#define G2_LD_B1(kb, par) do {                                  \
    gload_lds16(bR0 + (kb) + 32, Bs + PNL(par, 0, 1) + woff);   \
    gload_lds16(bR1 + (kb) + 32, Bs + PNL(par, 1, 1) + woff); } while (0)

#define G2_RDB(par, kc) do {                                                   \
    _Pragma("unroll")                                                          \
    for (int ni = 0; ni < 4; ni++)                                             \
      bfr[ni] = *(const bf16x8*)&Bs[PNL(par, (wn >> 1), kc) +                  \
                  ((wn & 1) * 64 + ni * 16 + fm) * 32 + fq];                   \
  } while (0)

#define G2_RDA(par, mq, kc) do {                                               \
    _Pragma("unroll")                                                          \
    for (int mi = 0; mi < 4; mi++)                                             \
      af[mi] = *(const bf16x8*)&As[PNL(par, wm, kc) +                          \
                                   ((mq) * 64 + mi * 16 + fm) * 32 + fq];      \
  } while (0)

#define G2_MFMA(mq) do {                                                       \
    __builtin_amdgcn_s_setprio(1);                                             \
    _Pragma("unroll")                                                          \
    for (int mi = 0; mi < 4; mi++) {                                           \
      _Pragma("unroll")                                                        \
      for (int ni = 0; ni < 4; ni++)                                           \
        acc[(mq) * 4 + mi][ni] = __builtin_amdgcn_mfma_f32_16x16x32_bf16(      \
            af[mi], bfr[ni], acc[(mq) * 4 + mi][ni], 0, 0, 0);                 \
    }                                                                          \
    __builtin_amdgcn_s_setprio(0);                                             \
  } while (0)

  // prologue: tile 0 (kc order); vmcnt(4)+BAR => kc0 readable pre-barrier
  G2_LD_A0(0, 0); G2_LD_B0(0, 0); G2_LD_A1(0, 0); G2_LD_B1(0, 0);
  WVM4;
  BAR;

  int par = 0;
#pragma unroll 1
  for (int t = 0; t < NT; ++t) {
    const bool nxt = (t + 1 < NT);
    const int kb = (t + 1) * 64;
    bf16x8 af[4], bfr[4];
    // ph0: kc0 mq0
    G2_RDB(par, 0); G2_RDA(par, 0, 0);
    if (nxt) G2_LD_A0(kb, par ^ 1);
    BAR; WAITL; G2_MFMA(0); BAR;
    // ph1: kc0 mq1; tail vmcnt readies kc1
    G2_RDA(par, 1, 0);
    if (nxt) { G2_LD_B0(kb, par ^ 1); WVM4; } else { WVM0; }
    BAR; WAITL; G2_MFMA(1); BAR;
    // ph2: kc1 mq0
    G2_RDB(par, 1); G2_RDA(par, 0, 1);
    if (nxt) G2_LD_A1(kb, par ^ 1);
    BAR; WAITL; G2_MFMA(0); BAR;
    // ph3: kc1 mq1; tail vmcnt readies next kc0
    G2_RDA(par, 1, 1);
    if (nxt) { G2_LD_B1(kb, par ^ 1); WVM4; }
    BAR; WAITL; G2_MFMA(1); BAR;
    par ^= 1;
  }
#undef G2_LD_A0
#undef G2_LD_B0
#undef G2_LD_A1
#undef G2_LD_B1
#undef G2_RDB
#undef G2_RDA
#undef G2_MFMA

  const int toffE = (e < 8) ? toff[e] : 0;
#pragma unroll
  for (int mg = 0; mg < 8; mg++) {
    const int rbase = wm * 128 + mg * 16 + ((lane >> 4) << 2);
#pragma unroll
    for (int r = 0; r < 4; r++) {
      const int rowIdx = rbase + r;
      const int token = tokLDS[rowIdx];
      if (token < 0) continue;
      if (compact) {
        __bf16* dst;
        float scale;
        if (e == 8) {
          dst = &Eo[(size_t)(16384 + token) * C_DIM];
          scale = 1.0f;
        } else {
          dst = &Eo[(size_t)(toffE + m0 + rowIdx) * C_DIM];
          scale = comb[(size_t)token * 8 + e];
        }
#pragma unroll
        for (int ni = 0; ni < 4; ni++) {
          const int c = n0 + wn * 64 + ni * 16 + fm;
          dst[c] = (__bf16)(scale * acc[mg][ni][r]);
        }
      } else {
        const float scale = (e == 8) ? 1.0f : comb[(size_t)token * 8 + e];
        if (scale != 0.0f) {
#pragma unroll
          for (int ni = 0; ni < 4; ni++) {
            const int c = n0 + wn * 64 + ni * 16 + fm;
            atomicAdd(&out[(size_t)token * C_DIM + c], scale * acc[mg][ni][r]);
          }
        }
      }
    }
  }
}

// ---------------------------------------------------------------------------
__global__ __launch_bounds__(256) void bias_init(
    const int2* __restrict__ sm, const float* __restrict__ sob,
    const float* __restrict__ eob, float* __restrict__ out) {
  const int wave = threadIdx.x >> 6, lane = threadIdx.x & 63;
  const int s = blockIdx.x * 4 + wave;
  const int c0 = lane * 8;
  const int2 m = sm[s];
  const int e0 = m.x >> 16;
  const float4 za = *(const float4*)(sob + c0);
  const float4 zb = *(const float4*)(sob + c0 + 4);
  const float4 ea = *(const float4*)(eob + e0 * C_DIM + c0);
  const float4 eb2 = *(const float4*)(eob + e0 * C_DIM + c0 + 4);
  float accv[8] = {za.x + ea.x, za.y + ea.y, za.z + ea.z, za.w + ea.w,
                   zb.x + eb2.x, zb.y + eb2.y, zb.z + eb2.z, zb.w + eb2.w};
  if (m.y >= 0) {
    const int e1 = m.y >> 16;
    const float4 fa = *(const float4*)(eob + e1 * C_DIM + c0);
    const float4 fb = *(const float4*)(eob + e1 * C_DIM + c0 + 4);
    accv[0] += fa.x; accv[1] += fa.y; accv[2] += fa.z; accv[3] += fa.w;
    accv[4] += fb.x; accv[5] += fb.y; accv[6] += fb.z; accv[7] += fb.w;
  }
  float* dst = out + (size_t)s * C_DIM + c0;
  *(float4*)(dst)     = make_float4(accv[0], accv[1], accv[2], accv[3]);
  *(float4*)(dst + 4) = make_float4(accv[4], accv[5], accv[6], accv[7]);
}

// ---------------------------------------------------------------------------
__global__ __launch_bounds__(256) void combine(
    const __bf16* __restrict__ Eo, const int2* __restrict__ sm,
    const int* __restrict__ toff, const float* __restrict__ sob,
    const float* __restrict__ eob, float* __restrict__ out) {
  const int wave = threadIdx.x >> 6, lane = threadIdx.x & 63;
  const int s = blockIdx.x * 4 + wave;
  const int c0 = lane * 8;
  const int2 m = sm[s];
  const int e0 = m.x >> 16, p0 = m.x & 0xffff;

  const bf16x8 vs = *(const bf16x8*)(Eo + (size_t)(16384 + s) * C_DIM + c0);
  const bf16x8 v0 = *(const bf16x8*)(Eo + (size_t)(toff[e0] + p0) * C_DIM + c0);
  const float4 za = *(const float4*)(sob + c0);
  const float4 zb = *(const float4*)(sob + c0 + 4);
  const float4 ea = *(const float4*)(eob + e0 * C_DIM + c0);
  const float4 eb2 = *(const float4*)(eob + e0 * C_DIM + c0 + 4);
  float accv[8] = {za.x + ea.x, za.y + ea.y, za.z + ea.z, za.w + ea.w,
                   zb.x + eb2.x, zb.y + eb2.y, zb.z + eb2.z, zb.w + eb2.w};
#pragma unroll
  for (int j = 0; j < 8; j++) accv[j] += (float)vs[j] + (float)v0[j];
  if (m.y >= 0) {
    const int e1 = m.y >> 16, p1 = m.y & 0xffff;
    const bf16x8 v1 = *(const bf16x8*)(Eo + (size_t)(toff[e1] + p1) * C_DIM + c0);
    const float4 fa = *(const float4*)(eob + e1 * C_DIM + c0);
    const float4 fb = *(const float4*)(eob + e1 * C_DIM + c0 + 4);
    const float b1[8] = {fa.x, fa.y, fa.z, fa.w, fb.x, fb.y, fb.z, fb.w};
#pragma unroll
    for (int j = 0; j < 8; j++) accv[j] += (float)v1[j] + b1[j];
  }
  float* dst = out + (size_t)s * C_DIM + c0;
  *(float4*)(dst)     = make_float4(accv[0], accv[1], accv[2], accv[3]);
  *(float4*)(dst + 4) = make_float4(accv[4], accv[5], accv[6], accv[7]);
}

// ---------------------------------------------------------------------------
extern "C" void kernel_launch(void* const* d_in, const int* in_sizes, int n_in,
                              void* d_out, int out_size, void* d_ws, size_t ws_size,
                              hipStream_t stream) {
  const float* x    = (const float*)d_in[0];
  const float* lns  = (const float*)d_in[1];
  const float* lnbi = (const float*)d_in[2];
  const float* siw  = (const float*)d_in[3];
  const float* sow  = (const float*)d_in[4];
  const float* sob  = (const float*)d_in[5];
  const float* eiw  = (const float*)d_in[6];
  const float* eow  = (const float*)d_in[7];
  const float* eob  = (const float*)d_in[8];
  const float* ggw  = (const float*)d_in[9];
  const float* egw  = (const float*)d_in[10];
  const float* gb   = (const float*)d_in[11];
  const float* eb   = (const float*)d_in[12];
  float* out = (float*)d_out;

  char* ws = (char*)d_ws;
  __bf16* w1   = (__bf16*)(ws);                 //  4,194,304  [4096,512]
  __bf16* w2   = (__bf16*)(ws + 4194304);       //  9,437,184  [9,512,1024]
  __bf16* lnb  = (__bf16*)(ws + 13631488);      //  8,388,608  [8192,512]
  __bf16* Hbuf = (__bf16*)(ws + 22020096);      // 33,554,432  [8192,2048]
  float*  comb = (float*)(ws + 55574528);       //    262,144  [8192,8]
  int*    tok  = (int*)(ws + 55836672);         //    262,144  [8,8192]
  int2*   sm   = (int2*)(ws + 56098816);        //     65,536  [8192]
  int*    cnt  = (int*)(ws + 56164352);         //         32  [8]
  int*    done = (int*)(ws + 56164384);         //          4  (cnt+8)
  int*    off  = (int*)(ws + 56164416);         //         36  [9]
  int*    toff = (int*)(ws + 56164452);         //         36  [9]
  __bf16* Eo   = (__bf16*)(ws + 56164512);      // 25,165,824  [24576,512]
  const size_t NEED = 81330336;
  const int compact = (ws_size >= NEED) ? 1 : 0;

  // ln_gate zeroes cnt[8]+done (contiguous) — no memset dispatch needed.
  ln_gate_wave<<<S_TOT / 4, 256, 0, stream>>>(x, lns, lnbi, ggw, egw, gb, eb,
                                              lnb, comb, cnt);

  cvt_fused<<<6656, 256, 0, stream>>>(siw, eiw, eow, sow, w1, w2);

  build_lists<<<S_TOT / 256, 256, 0, stream>>>(comb, cnt, tok, sm,
                                               done, off, toff);

  gemm1_swiglu<<<dim3(S_TOT / 256, 2 * H_DIM / 128), 512, 0, stream>>>(lnb, w1, Hbuf);

  if (!compact)
    bias_init<<<S_TOT / 4, 256, 0, stream>>>(sm, sob, eob, out);

  gemm2_moe<<<dim3(MAX_ET2 + 32, C_DIM / 256), 512, 0, stream>>>(
      Hbuf, w2, comb, cnt, tok, off, toff, Eo, out, compact);

  if (compact)
    combine<<<S_TOT / 4, 256, 0, stream>>>(Eo, sm, toff, sob, eob, out);
}

// Round 11
// 220.102 us; speedup vs baseline: 1.0030x; 1.0030x over previous
//
#include <hip/hip_runtime.h>
#include <hip/hip_bf16.h>
#include <cstdint>

// ---------------------------------------------------------------------------
// HierDSFeedForward: LN -> shared SwiGLU FFN + hierarchical top-2 MoE
// S=8192 tokens, C=512, H=1024, G=2 groups x EG=4 experts, K=2
// R18 (resubmit; previous attempt hit an infra failure, never measured):
//      3-round decomposition (R15/R16/R17) shows the LDS swizzle is
//      ASYMMETRIC: gemm2 −18us (gathered A-staging already 64B-fragmented,
//      so the source permute is free; conflict-free reads win big) but
//      gemm1 +15us (dense lnb/W1 staging loses request coalescing).
//      => swizzle gemm2 ONLY (R16's gemm2, verified correct); gemm1 stays
//      linear (R17/R15 version). ln_gate float kept (−5.3us, R17).
// ---------------------------------------------------------------------------

typedef __bf16 bf16x8 __attribute__((ext_vector_type(8)));
typedef __bf16 bf16x4 __attribute__((ext_vector_type(4)));
typedef float  f32x4  __attribute__((ext_vector_type(4)));

#define S_TOT 8192
#define C_DIM 512
#define H_DIM 1024
// max expert M-tiles at 256 rows: 16384/256 + 8 = 72
#define MAX_ET2 72

__device__ __forceinline__ void gload_lds16(const void* g, void* l) {
  __builtin_amdgcn_global_load_lds(
      (__attribute__((address_space(1))) void*)(void*)(g),
      (__attribute__((address_space(3))) void*)(l),
      16, 0, 0);
}

// panel base (elements): [par][half][panel] of 128x32 bf16 panels
#define PNL(par, h, p) ((((par) * 2 + (h)) * 2 + (p)) * 4096)

#define WAITL do { asm volatile("s_waitcnt lgkmcnt(0)" ::: "memory");          \
                   __builtin_amdgcn_sched_barrier(0); } while (0)
#define BAR __builtin_amdgcn_s_barrier()
#define WVM4 asm volatile("s_waitcnt vmcnt(4)" ::: "memory")
#define WVM0 asm volatile("s_waitcnt vmcnt(0)" ::: "memory")

// ---------------------------------------------------------------------------
__global__ __launch_bounds__(256) void cvt_fused(
    const float* __restrict__ siw, const float* __restrict__ eiw,
    const float* __restrict__ eow, const float* __restrict__ sow,
    __bf16* __restrict__ w1, __bf16* __restrict__ w2) {
  const int i = (blockIdx.x * 256 + threadIdx.x) * 4;
  const float* src;
  __bf16* dst;
  if (i < 2097152) {
    src = (i < 1048576) ? (siw + i) : (eiw + (i - 1048576));
    dst = w1 + i;
  } else {
    const int j = i - 2097152;
    src = (j < 4194304) ? (eow + j) : (sow + (j - 4194304));
    dst = w2 + j;
  }
  float4 v = *(const float4*)src;
  bf16x4 o;
  o[0] = (__bf16)v.x; o[1] = (__bf16)v.y; o[2] = (__bf16)v.z; o[3] = (__bf16)v.w;
  *(bf16x4*)dst = o;
}

// ---------------------------------------------------------------------------
// Wave-per-token LN + gating (float gating); block 0 zeroes cnt[8]+done.
__global__ __launch_bounds__(256) void ln_gate_wave(
    const float* __restrict__ x,
    const float* __restrict__ ln_scale, const float* __restrict__ ln_bias,
    const float* __restrict__ ggw, const float* __restrict__ egw,
    const float* __restrict__ gb, const float* __restrict__ eb,
    __bf16* __restrict__ lnb, float* __restrict__ comb,
    int* __restrict__ cntz)
{
  if (blockIdx.x == 0 && threadIdx.x < 9) cntz[threadIdx.x] = 0;  // cnt[8]+done

  const int wave = threadIdx.x >> 6, lane = threadIdx.x & 63;
  const int s = blockIdx.x * 4 + wave;
  const size_t rowb = (size_t)s * C_DIM;
  const int c0 = lane * 8;

  const float4 va = *(const float4*)(x + rowb + c0);
  const float4 vb = *(const float4*)(x + rowb + c0 + 4);
  float v[8] = {va.x, va.y, va.z, va.w, vb.x, vb.y, vb.z, vb.w};

  float sum = 0.f;
#pragma unroll
  for (int j = 0; j < 8; j++) sum += v[j];
#pragma unroll
  for (int o = 1; o < 64; o <<= 1) sum += __shfl_xor(sum, o, 64);
  const float mu = sum * (1.0f / 512.0f);

  float sq = 0.f;
#pragma unroll
  for (int j = 0; j < 8; j++) { const float d = v[j] - mu; sq += d * d; }
#pragma unroll
  for (int o = 1; o < 64; o <<= 1) sq += __shfl_xor(sq, o, 64);
  const float rs = rsqrtf(sq * (1.0f / 512.0f) + 1e-5f);

  const float4 sa = *(const float4*)(ln_scale + c0);
  const float4 sb = *(const float4*)(ln_scale + c0 + 4);
  const float4 ba = *(const float4*)(ln_bias + c0);
  const float4 bb = *(const float4*)(ln_bias + c0 + 4);
  const float sc[8] = {sa.x, sa.y, sa.z, sa.w, sb.x, sb.y, sb.z, sb.w};
  const float bi[8] = {ba.x, ba.y, ba.z, ba.w, bb.x, bb.y, bb.z, bb.w};

  float y[8];
  bf16x8 yb;
#pragma unroll
  for (int j = 0; j < 8; j++) {
    y[j] = (v[j] - mu) * rs * sc[j] + bi[j];
    yb[j] = (__bf16)y[j];
  }
  *(bf16x8*)(lnb + rowb + c0) = yb;

  float lg[10];
#pragma unroll
  for (int r = 0; r < 10; r++) {
    const float* W = (r < 2) ? (ggw + r * C_DIM + c0) : (egw + (r - 2) * C_DIM + c0);
    const float4 wa = *(const float4*)(W);
    const float4 wb = *(const float4*)(W + 4);
    const float w[8] = {wa.x, wa.y, wa.z, wa.w, wb.x, wb.y, wb.z, wb.w};
    float p = 0.0f;
#pragma unroll
    for (int j = 0; j < 8; j++) p = fmaf(y[j], w[j], p);
    lg[r] = p;
  }
#pragma unroll
  for (int o = 1; o < 64; o <<= 1) {
#pragma unroll
    for (int r = 0; r < 10; r++) lg[r] += __shfl_xor(lg[r], o, 64);
  }

  const float g0 = lg[0] + gb[0], g1 = lg[1] + gb[1];
  const int g = (g1 > g0) ? 1 : 0;
  float el[4], mx = -1e30f;
#pragma unroll
  for (int j = 0; j < 4; j++) {
    el[j] = lg[2 + g * 4 + j] + eb[g * 4 + j];
    mx = fmaxf(mx, el[j]);
  }
  float pr[4], ps = 0.0f;
#pragma unroll
  for (int j = 0; j < 4; j++) { pr[j] = __expf(el[j] - mx); ps += pr[j]; }
  int i0 = 0;
#pragma unroll
  for (int j = 1; j < 4; j++) if (pr[j] > pr[i0]) i0 = j;
  int i1 = -1;
#pragma unroll
  for (int j = 0; j < 4; j++) {
    if (j == i0) continue;
    if (i1 < 0 || pr[j] > pr[i1]) i1 = j;
  }
  const float p0 = pr[i0] / ps, p1 = pr[i1] / ps;
  const float nrm = p0 + p1 + 1e-8f;
  const int e0 = g * 4 + i0, e1 = g * 4 + i1;
  const float w0 = p0 / nrm;
  const float w1v = fmaxf(p1 / nrm, 1e-30f);  // e1 always dispatched (bias)

  if (lane < 8)
    comb[(size_t)s * 8 + lane] = (lane == e0) ? w0 : ((lane == e1) ? w1v : 0.0f);
}

// ---------------------------------------------------------------------------
// Expert-list build + slot map + fused prefix (256-row tiles).
__global__ __launch_bounds__(256) void build_lists(
    const float* __restrict__ comb, int* __restrict__ cnt,
    int* __restrict__ tok, int2* __restrict__ sm,
    int* __restrict__ done, int* __restrict__ off, int* __restrict__ toff) {
  __shared__ int lcnt[8], lbase[8];
  const int t = threadIdx.x;
  if (t < 8) lcnt[t] = 0;
  __syncthreads();
  const int s = blockIdx.x * 256 + t;
  const float* cr = comb + (size_t)s * 8;
  int e0 = -1, e1 = -1;
#pragma unroll
  for (int j = 0; j < 8; j++) {
    if (cr[j] != 0.0f) { if (e0 < 0) e0 = j; else e1 = j; }
  }
  const int l0 = atomicAdd(&lcnt[e0], 1);
  const int l1 = (e1 >= 0) ? atomicAdd(&lcnt[e1], 1) : 0;
  __syncthreads();
  if (t < 8) lbase[t] = atomicAdd(&cnt[t], lcnt[t]);
  __syncthreads();
  const int p0 = lbase[e0] + l0;
  tok[e0 * S_TOT + p0] = s;
  int smy = -1;
  if (e1 >= 0) {
    const int p1 = lbase[e1] + l1;
    tok[e1 * S_TOT + p1] = s;
    smy = (e1 << 16) | p1;
  }
  sm[s] = make_int2((e0 << 16) | p0, smy);

  __syncthreads();
  if (t == 0) {
    __threadfence();
    if (atomicAdd(done, 1) == (int)gridDim.x - 1) {
      __threadfence();
      int sacc = 0, ts = 0;
#pragma unroll
      for (int e = 0; e < 8; e++) {
        const int c = atomicAdd(&cnt[e], 0);
        off[e] = sacc;  sacc += (c + 255) >> 8;
        toff[e] = ts;   ts += c;
      }
      off[8] = sacc; toff[8] = ts;
    }
  }
}

// ---------------------------------------------------------------------------
// GEMM1 + fused SwiGLU, race-free 4-phase/K-tile, 256x(128h) tile.
// LINEAR LDS (no swizzle): dense lnb/W1 staging needs coalesced quads (R16).
__global__ __launch_bounds__(512, 1) void gemm1_swiglu(
    const __bf16* __restrict__ A,
    const __bf16* __restrict__ W1,
    __bf16* __restrict__ H)
{
  constexpr int K = C_DIM;    // 512
  constexpr int NT = K / 64;  // 8 K-tiles
  __shared__ __bf16 As[8 * 4096];   // 64 KB
  __shared__ __bf16 Bs[8 * 4096];   // 64 KB (half0=gate, half1=up)

  const int m0  = blockIdx.x * 256;
  const int hc0 = blockIdx.y * 128;
  const int garow0 = hc0 + (hc0 < 1024 ? 0 : 1024);

  const int tid = threadIdx.x, wave = tid >> 6, lane = tid & 63;
  const int wm = wave >> 2, wn = wave & 3;
  const int fm = lane & 15, fq = (lane >> 4) * 8;
  const int srow = wave * 16 + (lane >> 2);
  const int scol = (lane & 3) * 8;
  const int woff = wave * 512;

  const __bf16* aR0 = A  + (size_t)(m0 + srow) * K + scol;
  const __bf16* aR1 = A  + (size_t)(m0 + 128 + srow) * K + scol;
  const __bf16* bR0 = W1 + (size_t)(garow0 + srow) * K + scol;
  const __bf16* bR1 = W1 + (size_t)(garow0 + 1024 + srow) * K + scol;

  f32x4 accg[8][2] = {};
  f32x4 accu[8][2] = {};

#define G1_LD_A0(kb, par) do {                                  \
    gload_lds16(aR0 + (kb), As + PNL(par, 0, 0) + woff);        \
    gload_lds16(aR1 + (kb), As + PNL(par, 1, 0) + woff); } while (0)
#define G1_LD_B0(kb, par) do {                                  \
    gload_lds16(bR0 + (kb), Bs + PNL(par, 0, 0) + woff);        \
    gload_lds16(bR1 + (kb), Bs + PNL(par, 1, 0) + woff); } while (0)
#define G1_LD_A1(kb, par) do {                                  \
    gload_lds16(aR0 + (kb) + 32, As + PNL(par, 0, 1) + woff);   \
    gload_lds16(aR1 + (kb) + 32, As + PNL(par, 1, 1) + woff); } while (0)
#define G1_LD_B1(kb, par) do {                                  \
    gload_lds16(bR0 + (kb) + 32, Bs + PNL(par, 0, 1) + woff);   \
    gload_lds16(bR1 + (kb) + 32, Bs + PNL(par, 1, 1) + woff); } while (0)

#define G1_RDB(par, kc) do {                                                   \
    bg[0] = *(const bf16x8*)&Bs[PNL(par, 0, kc) + (wn * 32 + fm) * 32 + fq];   \
    bg[1] = *(const bf16x8*)&Bs[PNL(par, 0, kc) + (wn * 32 + 16 + fm) * 32 + fq];\
    bu[0] = *(const bf16x8*)&Bs[PNL(par, 1, kc) + (wn * 32 + fm) * 32 + fq];   \
    bu[1] = *(const bf16x8*)&Bs[PNL(par, 1, kc) + (wn * 32 + 16 + fm) * 32 + fq];\
  } while (0)

#define G1_RDA(par, mq, kc) do {                                               \
    _Pragma("unroll")                                                          \
    for (int mi = 0; mi < 4; mi++)                                             \
      af[mi] = *(const bf16x8*)&As[PNL(par, wm, kc) +                          \
                                   ((mq) * 64 + mi * 16 + fm) * 32 + fq];      \
  } while (0)

#define G1_MFMA(mq) do {                                                       \
    __builtin_amdgcn_s_setprio(1);                                             \
    _Pragma("unroll")                                                          \
    for (int mi = 0; mi < 4; mi++) {                                           \
      _Pragma("unroll")                                                        \
      for (int ni = 0; ni < 2; ni++) {                                         \
        accg[(mq) * 4 + mi][ni] = __builtin_amdgcn_mfma_f32_16x16x32_bf16(     \
            af[mi], bg[ni], accg[(mq) * 4 + mi][ni], 0, 0, 0);                 \
        accu[(mq) * 4 + mi][ni] = __builtin_amdgcn_mfma_f32_16x16x32_bf16(     \
            af[mi], bu[ni], accu[(mq) * 4 + mi][ni], 0, 0, 0);                 \
      }                                                                        \
    }                                                                          \
    __builtin_amdgcn_s_setprio(0);                                             \
  } while (0)

  // prologue: tile 0 (kc order); vmcnt(4)+BAR => kc0 readable pre-barrier
  G1_LD_A0(0, 0); G1_LD_B0(0, 0); G1_LD_A1(0, 0); G1_LD_B1(0, 0);
  WVM4;
  BAR;

  int par = 0;
#pragma unroll 1
  for (int t = 0; t < NT; ++t) {
    const bool nxt = (t + 1 < NT);
    const int kb = (t + 1) * 64;
    bf16x8 af[4], bg[2], bu[2];
    // ph0: kc0 mq0 (ready via prev ph3's vmcnt(4)+BAR)
    G1_RDB(par, 0); G1_RDA(par, 0, 0);
    if (nxt) G1_LD_A0(kb, par ^ 1);
    BAR; WAITL; G1_MFMA(0); BAR;
    // ph1: kc0 mq1; tail vmcnt makes kc1 ready across waves after BAR
    G1_RDA(par, 1, 0);
    if (nxt) { G1_LD_B0(kb, par ^ 1); WVM4; } else { WVM0; }
    BAR; WAITL; G1_MFMA(1); BAR;
    // ph2: kc1 mq0
    G1_RDB(par, 1); G1_RDA(par, 0, 1);
    if (nxt) G1_LD_A1(kb, par ^ 1);
    BAR; WAITL; G1_MFMA(0); BAR;
    // ph3: kc1 mq1; tail vmcnt makes next tile's kc0 ready after BAR
    G1_RDA(par, 1, 1);
    if (nxt) { G1_LD_B1(kb, par ^ 1); WVM4; }
    BAR; WAITL; G1_MFMA(1); BAR;
    par ^= 1;
  }
#undef G1_LD_A0
#undef G1_LD_B0
#undef G1_LD_A1
#undef G1_LD_B1
#undef G1_RDB
#undef G1_RDA
#undef G1_MFMA

#pragma unroll
  for (int mg = 0; mg < 8; mg++) {
    const int row0 = m0 + wm * 128 + mg * 16 + ((lane >> 4) << 2);
#pragma unroll
    for (int ni = 0; ni < 2; ni++) {
      const int c = hc0 + wn * 32 + ni * 16 + fm;
#pragma unroll
      for (int r = 0; r < 4; r++) {
        const float a = accg[mg][ni][r];
        const float b = accu[mg][ni][r];
        const float sv = a / (1.0f + __expf(-a));
        H[(size_t)(row0 + r) * (2 * H_DIM) + c] = (__bf16)(sv * b);
      }
    }
  }
}

// ---------------------------------------------------------------------------
// Unified GEMM2, race-free 4-phase/K-tile, 256x256 tile, gathered A.
// SWIZZLED LDS (R16 gemm2): gathered staging is already 64B-fragmented, so
// the source permute is free and conflict-free reads are a large win.
__global__ __launch_bounds__(512, 1) void gemm2_moe(
    const __bf16* __restrict__ Hb,   // [8192, 2048]
    const __bf16* __restrict__ W2,   // [9, 512, 1024]
    const float* __restrict__ comb,  // [8192, 8]
    const int* __restrict__ cnt,     // [8]
    const int* __restrict__ tok,     // [8, 8192]
    const int* __restrict__ off,     // [9] tile prefix (256-row tiles)
    const int* __restrict__ toff,    // [9] token prefix
    __bf16* __restrict__ Eo,         // [24576, 512]
    float* __restrict__ out,         // fallback only
    int compact)
{
  constexpr int K = H_DIM;    // 1024
  constexpr int NT = K / 64;  // 16 K-tiles
  __shared__ __bf16 As[8 * 4096];
  __shared__ __bf16 Bs[8 * 4096];
  __shared__ int tokLDS[256];

  const int g = blockIdx.x;
  const int T = off[8];
  int e, m0;
  if (g < T) {
    e = 0;
    while (e < 7 && g >= off[e + 1]) e++;
    m0 = (g - off[e]) * 256;
  } else if (g < T + 32) {
    e = 8;
    m0 = (g - T) * 256;
  } else {
    return;
  }
  const int cnt_e = (e == 8) ? S_TOT : cnt[e];
  const int n0 = blockIdx.y * 256;
  const __bf16* Bw = W2 + (size_t)e * C_DIM * H_DIM;
  const int abase = (e == 8) ? 0 : H_DIM;

  const int tid = threadIdx.x, wave = tid >> 6, lane = tid & 63;
  const int wm = wave >> 2, wn = wave & 3;
  const int fm = lane & 15, fq = (lane >> 4) * 8;
  const int fqs = fq ^ (((fm >> 1) & 3) << 3);              // read side
  const int srow = wave * 16 + (lane >> 2);
  const int scol = (((lane & 3) ^ ((lane >> 3) & 3)) * 8);  // source side
  const int woff = wave * 512;

  if (tid < 256) {
    const int r = m0 + tid;
    tokLDS[tid] = (e == 8) ? r : ((r < cnt_e) ? tok[e * S_TOT + r] : -1);
  }
  __syncthreads();   // tokLDS visible; vmcnt clean before pipelined loop

  int tk0 = tokLDS[srow];       if (tk0 < 0) tk0 = 0;
  int tk1 = tokLDS[128 + srow]; if (tk1 < 0) tk1 = 0;
  const __bf16* aR0 = Hb + abase + (size_t)tk0 * (2 * H_DIM) + scol;
  const __bf16* aR1 = Hb + abase + (size_t)tk1 * (2 * H_DIM) + scol;
  const __bf16* bR0 = Bw + (size_t)(n0 + srow) * K + scol;
  const __bf16* bR1 = Bw + (size_t)(n0 + 128 + srow) * K + scol;

  f32x4 acc[8][4] = {};

#define G2_LD_A0(kb, par) do {                                  \
    gload_lds16(aR0 + (kb), As + PNL(par, 0, 0) + woff);        \
    gload_lds16(aR1 + (kb), As + PNL(par, 1, 0) + woff); } while (0)
#define G2_LD_B0(kb, par) do {                                  \
    gload_lds16(bR0 + (kb), Bs + PNL(par, 0, 0) + woff);        \
    gload_lds16(bR1 + (kb), Bs + PNL(par, 1, 0) + woff); } while (0)
#define G2_LD_A1(kb, par) do {                                  \
    gload_lds16(aR0 + (kb) + 32, As + PNL(par, 0, 1) + woff);   \
    gload_lds16(aR1 + (kb) + 32, As + PNL(par, 1, 1) + woff); } while (0)
#define G2_LD_B1(kb, par) do {                                  \
    gload_lds16(bR0 + (kb) + 32, Bs + PNL(par, 0, 1) + woff);   \
    gload_lds16(bR1 + (kb) + 32, Bs + PNL(par, 1, 1) + woff); } while (0)

#define G2_RDB(par, kc) do {                                                   \
    _Pragma("unroll")                                                          \
    for (int ni = 0; ni < 4; ni++)                                             \
      bfr[ni] = *(const bf16x8*)&Bs[PNL(par, (wn >> 1), kc) +                  \
                  ((wn & 1) * 64 + ni * 16 + fm) * 32 + fqs];                  \
  } while (0)

#define G2_RDA(par, mq, kc) do {                                               \
    _Pragma("unroll")                                                          \
    for (int mi = 0; mi < 4; mi++)                                             \
      af[mi] = *(const bf16x8*)&As[PNL(par, wm, kc) +                          \
                                   ((mq) * 64 + mi * 16 + fm) * 32 + fqs];     \
  } while (0)

#define G2_MFMA(mq) do {                                                       \
    __builtin_amdgcn_s_setprio(1);                                             \
    _Pragma("unroll")                                                          \
    for (int mi = 0; mi < 4; mi++) {                                           \
      _Pragma("unroll")                                                        \
      for (int ni = 0; ni < 4; ni++)                                           \
        acc[(mq) * 4 + mi][ni] = __builtin_amdgcn_mfma_f32_16x16x32_bf16(      \
            af[mi], bfr[ni], acc[(mq) * 4 + mi][ni], 0, 0, 0);                 \
    }                                                                          \
    __builtin_amdgcn_s_setprio(0);                                             \
  } while (0)

  // prologue: tile 0 (kc order); vmcnt(4)+BAR => kc0 readable pre-barrier
  G2_LD_A0(0, 0); G2_LD_B0(0, 0); G2_LD_A1(0, 0); G2_LD_B1(0, 0);
  WVM4;
  BAR;

  int par = 0;
#pragma unroll 1
  for (int t = 0; t < NT; ++t) {
    const bool nxt = (t + 1 < NT);
    const int kb = (t + 1) * 64;
    bf16x8 af[4], bfr[4];
    // ph0: kc0 mq0
    G2_RDB(par, 0); G2_RDA(par, 0, 0);
    if (nxt) G2_LD_A0(kb, par ^ 1);
    BAR; WAITL; G2_MFMA(0); BAR;
    // ph1: kc0 mq1; tail vmcnt readies kc1
    G2_RDA(par, 1, 0);
    if (nxt) { G2_LD_B0(kb, par ^ 1); WVM4; } else { WVM0; }
    BAR; WAITL; G2_MFMA(1); BAR;
    // ph2: kc1 mq0
    G2_RDB(par, 1); G2_RDA(par, 0, 1);
    if (nxt) G2_LD_A1(kb, par ^ 1);
    BAR; WAITL; G2_MFMA(0); BAR;
    // ph3: kc1 mq1; tail vmcnt readies next kc0
    G2_RDA(par, 1, 1);
    if (nxt) { G2_LD_B1(kb, par ^ 1); WVM4; }
    BAR; WAITL; G2_MFMA(1); BAR;
    par ^= 1;
  }
#undef G2_LD_A0
#undef G2_LD_B0
#undef G2_LD_A1
#undef G2_LD_B1
#undef G2_RDB
#undef G2_RDA
#undef G2_MFMA

  const int toffE = (e < 8) ? toff[e] : 0;
#pragma unroll
  for (int mg = 0; mg < 8; mg++) {
    const int rbase = wm * 128 + mg * 16 + ((lane >> 4) << 2);
#pragma unroll
    for (int r = 0; r < 4; r++) {
      const int rowIdx = rbase + r;
      const int token = tokLDS[rowIdx];
      if (token < 0) continue;
      if (compact) {
        __bf16* dst;
        float scale;
        if (e == 8) {
          dst = &Eo[(size_t)(16384 + token) * C_DIM];
          scale = 1.0f;
        } else {
          dst = &Eo[(size_t)(toffE + m0 + rowIdx) * C_DIM];
          scale = comb[(size_t)token * 8 + e];
        }
#pragma unroll
        for (int ni = 0; ni < 4; ni++) {
          const int c = n0 + wn * 64 + ni * 16 + fm;
          dst[c] = (__bf16)(scale * acc[mg][ni][r]);
        }
      } else {
        const float scale = (e == 8) ? 1.0f : comb[(size_t)token * 8 + e];
        if (scale != 0.0f) {
#pragma unroll
          for (int ni = 0; ni < 4; ni++) {
            const int c = n0 + wn * 64 + ni * 16 + fm;
            atomicAdd(&out[(size_t)token * C_DIM + c], scale * acc[mg][ni][r]);
          }
        }
      }
    }
  }
}

// ---------------------------------------------------------------------------
__global__ __launch_bounds__(256) void bias_init(
    const int2* __restrict__ sm, const float* __restrict__ sob,
    const float* __restrict__ eob, float* __restrict__ out) {
  const int wave = threadIdx.x >> 6, lane = threadIdx.x & 63;
  const int s = blockIdx.x * 4 + wave;
  const int c0 = lane * 8;
  const int2 m = sm[s];
  const int e0 = m.x >> 16;
  const float4 za = *(const float4*)(sob + c0);
  const float4 zb = *(const float4*)(sob + c0 + 4);
  const float4 ea = *(const float4*)(eob + e0 * C_DIM + c0);
  const float4 eb2 = *(const float4*)(eob + e0 * C_DIM + c0 + 4);
  float accv[8] = {za.x + ea.x, za.y + ea.y, za.z + ea.z, za.w + ea.w,
                   zb.x + eb2.x, zb.y + eb2.y, zb.z + eb2.z, zb.w + eb2.w};
  if (m.y >= 0) {
    const int e1 = m.y >> 16;
    const float4 fa = *(const float4*)(eob + e1 * C_DIM + c0);
    const float4 fb = *(const float4*)(eob + e1 * C_DIM + c0 + 4);
    accv[0] += fa.x; accv[1] += fa.y; accv[2] += fa.z; accv[3] += fa.w;
    accv[4] += fb.x; accv[5] += fb.y; accv[6] += fb.z; accv[7] += fb.w;
  }
  float* dst = out + (size_t)s * C_DIM + c0;
  *(float4*)(dst)     = make_float4(accv[0], accv[1], accv[2], accv[3]);
  *(float4*)(dst + 4) = make_float4(accv[4], accv[5], accv[6], accv[7]);
}

// ---------------------------------------------------------------------------
__global__ __launch_bounds__(256) void combine(
    const __bf16* __restrict__ Eo, const int2* __restrict__ sm,
    const int* __restrict__ toff, const float* __restrict__ sob,
    const float* __restrict__ eob, float* __restrict__ out) {
  const int wave = threadIdx.x >> 6, lane = threadIdx.x & 63;
  const int s = blockIdx.x * 4 + wave;
  const int c0 = lane * 8;
  const int2 m = sm[s];
  const int e0 = m.x >> 16, p0 = m.x & 0xffff;

  const bf16x8 vs = *(const bf16x8*)(Eo + (size_t)(16384 + s) * C_DIM + c0);
  const bf16x8 v0 = *(const bf16x8*)(Eo + (size_t)(toff[e0] + p0) * C_DIM + c0);
  const float4 za = *(const float4*)(sob + c0);
  const float4 zb = *(const float4*)(sob + c0 + 4);
  const float4 ea = *(const float4*)(eob + e0 * C_DIM + c0);
  const float4 eb2 = *(const float4*)(eob + e0 * C_DIM + c0 + 4);
  float accv[8] = {za.x + ea.x, za.y + ea.y, za.z + ea.z, za.w + ea.w,
                   zb.x + eb2.x, zb.y + eb2.y, zb.z + eb2.z, zb.w + eb2.w};
#pragma unroll
  for (int j = 0; j < 8; j++) accv[j] += (float)vs[j] + (float)v0[j];
  if (m.y >= 0) {
    const int e1 = m.y >> 16, p1 = m.y & 0xffff;
    const bf16x8 v1 = *(const bf16x8*)(Eo + (size_t)(toff[e1] + p1) * C_DIM + c0);
    const float4 fa = *(const float4*)(eob + e1 * C_DIM + c0);
    const float4 fb = *(const float4*)(eob + e1 * C_DIM + c0 + 4);
    const float b1[8] = {fa.x, fa.y, fa.z, fa.w, fb.x, fb.y, fb.z, fb.w};
#pragma unroll
    for (int j = 0; j < 8; j++) accv[j] += (float)v1[j] + b1[j];
  }
  float* dst = out + (size_t)s * C_DIM + c0;
  *(float4*)(dst)     = make_float4(accv[0], accv[1], accv[2], accv[3]);
  *(float4*)(dst + 4) = make_float4(accv[4], accv[5], accv[6], accv[7]);
}

// ---------------------------------------------------------------------------
extern "C" void kernel_launch(void* const* d_in, const int* in_sizes, int n_in,
                              void* d_out, int out_size, void* d_ws, size_t ws_size,
                              hipStream_t stream) {
  const float* x    = (const float*)d_in[0];
  const float* lns  = (const float*)d_in[1];
  const float* lnbi = (const float*)d_in[2];
  const float* siw  = (const float*)d_in[3];
  const float* sow  = (const float*)d_in[4];
  const float* sob  = (const float*)d_in[5];
  const float* eiw  = (const float*)d_in[6];
  const float* eow  = (const float*)d_in[7];
  const float* eob  = (const float*)d_in[8];
  const float* ggw  = (const float*)d_in[9];
  const float* egw  = (const float*)d_in[10];
  const float* gb   = (const float*)d_in[11];
  const float* eb   = (const float*)d_in[12];
  float* out = (float*)d_out;

  char* ws = (char*)d_ws;
  __bf16* w1   = (__bf16*)(ws);                 //  4,194,304  [4096,512]
  __bf16* w2   = (__bf16*)(ws + 4194304);       //  9,437,184  [9,512,1024]
  __bf16* lnb  = (__bf16*)(ws + 13631488);      //  8,388,608  [8192,512]
  __bf16* Hbuf = (__bf16*)(ws + 22020096);      // 33,554,432  [8192,2048]
  float*  comb = (float*)(ws + 55574528);       //    262,144  [8192,8]
  int*    tok  = (int*)(ws + 55836672);         //    262,144  [8,8192]
  int2*   sm   = (int2*)(ws + 56098816);        //     65,536  [8192]
  int*    cnt  = (int*)(ws + 56164352);         //         32  [8]
  int*    done = (int*)(ws + 56164384);         //          4  (cnt+8)
  int*    off  = (int*)(ws + 56164416);         //         36  [9]
  int*    toff = (int*)(ws + 56164452);         //         36  [9]
  __bf16* Eo   = (__bf16*)(ws + 56164512);      // 25,165,824  [24576,512]
  const size_t NEED = 81330336;
  const int compact = (ws_size >= NEED) ? 1 : 0;

  // ln_gate zeroes cnt[8]+done (contiguous) — no memset dispatch needed.
  ln_gate_wave<<<S_TOT / 4, 256, 0, stream>>>(x, lns, lnbi, ggw, egw, gb, eb,
                                              lnb, comb, cnt);

  cvt_fused<<<6656, 256, 0, stream>>>(siw, eiw, eow, sow, w1, w2);

  build_lists<<<S_TOT / 256, 256, 0, stream>>>(comb, cnt, tok, sm,
                                               done, off, toff);

  gemm1_swiglu<<<dim3(S_TOT / 256, 2 * H_DIM / 128), 512, 0, stream>>>(lnb, w1, Hbuf);

  if (!compact)
    bias_init<<<S_TOT / 4, 256, 0, stream>>>(sm, sob, eob, out);

  gemm2_moe<<<dim3(MAX_ET2 + 32, C_DIM / 256), 512, 0, stream>>>(
      Hbuf, w2, comb, cnt, tok, off, toff, Eo, out, compact);

  if (compact)
    combine<<<S_TOT / 4, 256, 0, stream>>>(Eo, sm, toff, sob, eob, out);
}

// Round 12
// 210.511 us; speedup vs baseline: 1.0487x; 1.0456x over previous
//
#include <hip/hip_runtime.h>
#include <hip/hip_bf16.h>
#include <cstdint>

// ---------------------------------------------------------------------------
// HierDSFeedForward: LN -> shared SwiGLU FFN + hierarchical top-2 MoE
// S=8192 tokens, C=512, H=1024, G=2 groups x EG=4 experts, K=2
// R19: R18 resolved the swizzle story (gemm1 +15us, gemm2 neutral; totals
//      across rounds sit in a +-2% noise band so the R16 "-18us" inference
//      was GIGO). The invariant ~115us aux tail (traffic worth ~35us, immune
//      to a 32MB cut) implicates per-launch fixed overhead. This round cuts
//      dispatches 6 -> 4 with GEMM bodies untouched:
//        A: ln_gate + cvt fused (grid-partitioned, independent work)
//        B: gemm1 with build_lists embedded in blocks (y==0, x<16)
//        C: gemm2 (R18 body, swizzled)   D: combine
// ---------------------------------------------------------------------------

typedef __bf16 bf16x8 __attribute__((ext_vector_type(8)));
typedef __bf16 bf16x4 __attribute__((ext_vector_type(4)));
typedef float  f32x4  __attribute__((ext_vector_type(4)));

#define S_TOT 8192
#define C_DIM 512
#define H_DIM 1024
// max expert M-tiles at 256 rows: 16384/256 + 8 = 72
#define MAX_ET2 72

__device__ __forceinline__ void gload_lds16(const void* g, void* l) {
  __builtin_amdgcn_global_load_lds(
      (__attribute__((address_space(1))) void*)(void*)(g),
      (__attribute__((address_space(3))) void*)(l),
      16, 0, 0);
}

// panel base (elements): [par][half][panel] of 128x32 bf16 panels
#define PNL(par, h, p) ((((par) * 2 + (h)) * 2 + (p)) * 4096)

#define WAITL do { asm volatile("s_waitcnt lgkmcnt(0)" ::: "memory");          \
                   __builtin_amdgcn_sched_barrier(0); } while (0)
#define BAR __builtin_amdgcn_s_barrier()
#define WVM4 asm volatile("s_waitcnt vmcnt(4)" ::: "memory")
#define WVM0 asm volatile("s_waitcnt vmcnt(0)" ::: "memory")

// ---------------------------------------------------------------------------
// Fused: blocks [0,2048) = wave-per-token LN + gating (float math);
//        blocks [2048,8704) = fp32->bf16 weight conversion.
// Block 0 zeroes cnt[8]+done (9 contiguous ints).
__global__ __launch_bounds__(256) void ln_gate_cvt(
    const float* __restrict__ x,
    const float* __restrict__ ln_scale, const float* __restrict__ ln_bias,
    const float* __restrict__ ggw, const float* __restrict__ egw,
    const float* __restrict__ gb, const float* __restrict__ eb,
    __bf16* __restrict__ lnb, float* __restrict__ comb,
    int* __restrict__ cntz,
    const float* __restrict__ siw, const float* __restrict__ eiw,
    const float* __restrict__ eow, const float* __restrict__ sow,
    __bf16* __restrict__ w1, __bf16* __restrict__ w2)
{
  if (blockIdx.x >= 2048) {
    // ---- cvt path ----
    const int i = ((blockIdx.x - 2048) * 256 + threadIdx.x) * 4;
    const float* src;
    __bf16* dst;
    if (i < 2097152) {
      src = (i < 1048576) ? (siw + i) : (eiw + (i - 1048576));
      dst = w1 + i;
    } else {
      const int j = i - 2097152;
      src = (j < 4194304) ? (eow + j) : (sow + (j - 4194304));
      dst = w2 + j;
    }
    float4 v = *(const float4*)src;
    bf16x4 o;
    o[0] = (__bf16)v.x; o[1] = (__bf16)v.y; o[2] = (__bf16)v.z; o[3] = (__bf16)v.w;
    *(bf16x4*)dst = o;
    return;
  }

  // ---- LN + gating path ----
  if (blockIdx.x == 0 && threadIdx.x < 9) cntz[threadIdx.x] = 0;  // cnt[8]+done

  const int wave = threadIdx.x >> 6, lane = threadIdx.x & 63;
  const int s = blockIdx.x * 4 + wave;
  const size_t rowb = (size_t)s * C_DIM;
  const int c0 = lane * 8;

  const float4 va = *(const float4*)(x + rowb + c0);
  const float4 vb = *(const float4*)(x + rowb + c0 + 4);
  float v[8] = {va.x, va.y, va.z, va.w, vb.x, vb.y, vb.z, vb.w};

  float sum = 0.f;
#pragma unroll
  for (int j = 0; j < 8; j++) sum += v[j];
#pragma unroll
  for (int o = 1; o < 64; o <<= 1) sum += __shfl_xor(sum, o, 64);
  const float mu = sum * (1.0f / 512.0f);

  float sq = 0.f;
#pragma unroll
  for (int j = 0; j < 8; j++) { const float d = v[j] - mu; sq += d * d; }
#pragma unroll
  for (int o = 1; o < 64; o <<= 1) sq += __shfl_xor(sq, o, 64);
  const float rs = rsqrtf(sq * (1.0f / 512.0f) + 1e-5f);

  const float4 sa = *(const float4*)(ln_scale + c0);
  const float4 sb = *(const float4*)(ln_scale + c0 + 4);
  const float4 ba = *(const float4*)(ln_bias + c0);
  const float4 bb = *(const float4*)(ln_bias + c0 + 4);
  const float sc[8] = {sa.x, sa.y, sa.z, sa.w, sb.x, sb.y, sb.z, sb.w};
  const float bi[8] = {ba.x, ba.y, ba.z, ba.w, bb.x, bb.y, bb.z, bb.w};

  float y[8];
  bf16x8 yb;
#pragma unroll
  for (int j = 0; j < 8; j++) {
    y[j] = (v[j] - mu) * rs * sc[j] + bi[j];
    yb[j] = (__bf16)y[j];
  }
  *(bf16x8*)(lnb + rowb + c0) = yb;

  float lg[10];
#pragma unroll
  for (int r = 0; r < 10; r++) {
    const float* W = (r < 2) ? (ggw + r * C_DIM + c0) : (egw + (r - 2) * C_DIM + c0);
    const float4 wa = *(const float4*)(W);
    const float4 wb = *(const float4*)(W + 4);
    const float w[8] = {wa.x, wa.y, wa.z, wa.w, wb.x, wb.y, wb.z, wb.w};
    float p = 0.0f;
#pragma unroll
    for (int j = 0; j < 8; j++) p = fmaf(y[j], w[j], p);
    lg[r] = p;
  }
#pragma unroll
  for (int o = 1; o < 64; o <<= 1) {
#pragma unroll
    for (int r = 0; r < 10; r++) lg[r] += __shfl_xor(lg[r], o, 64);
  }

  const float g0 = lg[0] + gb[0], g1 = lg[1] + gb[1];
  const int g = (g1 > g0) ? 1 : 0;
  float el[4], mx = -1e30f;
#pragma unroll
  for (int j = 0; j < 4; j++) {
    el[j] = lg[2 + g * 4 + j] + eb[g * 4 + j];
    mx = fmaxf(mx, el[j]);
  }
  float pr[4], ps = 0.0f;
#pragma unroll
  for (int j = 0; j < 4; j++) { pr[j] = __expf(el[j] - mx); ps += pr[j]; }
  int i0 = 0;
#pragma unroll
  for (int j = 1; j < 4; j++) if (pr[j] > pr[i0]) i0 = j;
  int i1 = -1;
#pragma unroll
  for (int j = 0; j < 4; j++) {
    if (j == i0) continue;
    if (i1 < 0 || pr[j] > pr[i1]) i1 = j;
  }
  const float p0 = pr[i0] / ps, p1 = pr[i1] / ps;
  const float nrm = p0 + p1 + 1e-8f;
  const int e0 = g * 4 + i0, e1 = g * 4 + i1;
  const float w0 = p0 / nrm;
  const float w1v = fmaxf(p1 / nrm, 1e-30f);  // e1 always dispatched (bias)

  if (lane < 8)
    comb[(size_t)s * 8 + lane] = (lane == e0) ? w0 : ((lane == e1) ? w1v : 0.0f);
}

// ---------------------------------------------------------------------------
// GEMM1 + fused SwiGLU, race-free 4-phase/K-tile, 256x(128h) tile.
// LINEAR LDS (no swizzle). Blocks (y==0, x<16) first run the embedded
// expert-list build (512 tokens each, one per thread); last builder does
// the tile/token prefixes. gemm2 launches after gemm1 => tok/off visible.
__global__ __launch_bounds__(512, 1) void gemm1_swiglu(
    const __bf16* __restrict__ A,
    const __bf16* __restrict__ W1,
    __bf16* __restrict__ H,
    const float* __restrict__ comb,  // [8192,8]
    int* __restrict__ cnt,           // [8]
    int* __restrict__ tok,           // [8,8192]
    int2* __restrict__ sm,           // [8192]
    int* __restrict__ done,          // [1]
    int* __restrict__ off,           // [9]
    int* __restrict__ toff)          // [9]
{
  constexpr int K = C_DIM;    // 512
  constexpr int NT = K / 64;  // 8 K-tiles
  __shared__ __bf16 As[8 * 4096];   // 64 KB
  __shared__ __bf16 Bs[8 * 4096];   // 64 KB (half0=gate, half1=up)
  __shared__ int lcnt[8], lbase[8];

  // ---- embedded build_lists (16 builder blocks x 512 tokens) ----
  if (blockIdx.y == 0 && blockIdx.x < 16) {
    const int t = threadIdx.x;
    if (t < 8) lcnt[t] = 0;
    __syncthreads();
    const int s = blockIdx.x * 512 + t;
    const float* cr = comb + (size_t)s * 8;
    int e0 = -1, e1 = -1;
#pragma unroll
    for (int j = 0; j < 8; j++) {
      if (cr[j] != 0.0f) { if (e0 < 0) e0 = j; else e1 = j; }
    }
    const int l0 = atomicAdd(&lcnt[e0], 1);
    const int l1 = (e1 >= 0) ? atomicAdd(&lcnt[e1], 1) : 0;
    __syncthreads();
    if (t < 8) lbase[t] = atomicAdd(&cnt[t], lcnt[t]);
    __syncthreads();
    const int p0 = lbase[e0] + l0;
    tok[e0 * S_TOT + p0] = s;
    int smy = -1;
    if (e1 >= 0) {
      const int p1 = lbase[e1] + l1;
      tok[e1 * S_TOT + p1] = s;
      smy = (e1 << 16) | p1;
    }
    sm[s] = make_int2((e0 << 16) | p0, smy);
    __syncthreads();
    if (t == 0) {
      __threadfence();
      if (atomicAdd(done, 1) == 15) {
        __threadfence();
        int sacc = 0, ts = 0;
#pragma unroll
        for (int e = 0; e < 8; e++) {
          const int c = atomicAdd(&cnt[e], 0);
          off[e] = sacc;  sacc += (c + 255) >> 8;
          toff[e] = ts;   ts += c;
        }
        off[8] = sacc; toff[8] = ts;
      }
    }
    __syncthreads();
  }

  const int m0  = blockIdx.x * 256;
  const int hc0 = blockIdx.y * 128;
  const int garow0 = hc0 + (hc0 < 1024 ? 0 : 1024);

  const int tid = threadIdx.x, wave = tid >> 6, lane = tid & 63;
  const int wm = wave >> 2, wn = wave & 3;
  const int fm = lane & 15, fq = (lane >> 4) * 8;
  const int srow = wave * 16 + (lane >> 2);
  const int scol = (lane & 3) * 8;
  const int woff = wave * 512;

  const __bf16* aR0 = A  + (size_t)(m0 + srow) * K + scol;
  const __bf16* aR1 = A  + (size_t)(m0 + 128 + srow) * K + scol;
  const __bf16* bR0 = W1 + (size_t)(garow0 + srow) * K + scol;
  const __bf16* bR1 = W1 + (size_t)(garow0 + 1024 + srow) * K + scol;

  f32x4 accg[8][2] = {};
  f32x4 accu[8][2] = {};

#define G1_LD_A0(kb, par) do {                                  \
    gload_lds16(aR0 + (kb), As + PNL(par, 0, 0) + woff);        \
    gload_lds16(aR1 + (kb), As + PNL(par, 1, 0) + woff); } while (0)
#define G1_LD_B0(kb, par) do {                                  \
    gload_lds16(bR0 + (kb), Bs + PNL(par, 0, 0) + woff);        \
    gload_lds16(bR1 + (kb), Bs + PNL(par, 1, 0) + woff); } while (0)
#define G1_LD_A1(kb, par) do {                                  \
    gload_lds16(aR0 + (kb) + 32, As + PNL(par, 0, 1) + woff);   \
    gload_lds16(aR1 + (kb) + 32, As + PNL(par, 1, 1) + woff); } while (0)
#define G1_LD_B1(kb, par) do {                                  \
    gload_lds16(bR0 + (kb) + 32, Bs + PNL(par, 0, 1) + woff);   \
    gload_lds16(bR1 + (kb) + 32, Bs + PNL(par, 1, 1) + woff); } while (0)

#define G1_RDB(par, kc) do {                                                   \
    bg[0] = *(const bf16x8*)&Bs[PNL(par, 0, kc) + (wn * 32 + fm) * 32 + fq];   \
    bg[1] = *(const bf16x8*)&Bs[PNL(par, 0, kc) + (wn * 32 + 16 + fm) * 32 + fq];\
    bu[0] = *(const bf16x8*)&Bs[PNL(par, 1, kc) + (wn * 32 + fm) * 32 + fq];   \
    bu[1] = *(const bf16x8*)&Bs[PNL(par, 1, kc) + (wn * 32 + 16 + fm) * 32 + fq];\
  } while (0)

#define G1_RDA(par, mq, kc) do {                                               \
    _Pragma("unroll")                                                          \
    for (int mi = 0; mi < 4; mi++)                                             \
      af[mi] = *(const bf16x8*)&As[PNL(par, wm, kc) +                          \
                                   ((mq) * 64 + mi * 16 + fm) * 32 + fq];      \
  } while (0)

#define G1_MFMA(mq) do {                                                       \
    __builtin_amdgcn_s_setprio(1);                                             \
    _Pragma("unroll")                                                          \
    for (int mi = 0; mi < 4; mi++) {                                           \
      _Pragma("unroll")                                                        \
      for (int ni = 0; ni < 2; ni++) {                                         \
        accg[(mq) * 4 + mi][ni] = __builtin_amdgcn_mfma_f32_16x16x32_bf16(     \
            af[mi], bg[ni], accg[(mq) * 4 + mi][ni], 0, 0, 0);                 \
        accu[(mq) * 4 + mi][ni] = __builtin_amdgcn_mfma_f32_16x16x32_bf16(     \
            af[mi], bu[ni], accu[(mq) * 4 + mi][ni], 0, 0, 0);                 \
      }                                                                        \
    }                                                                          \
    __builtin_amdgcn_s_setprio(0);                                             \
  } while (0)

  // prologue: tile 0 (kc order); vmcnt(4)+BAR => kc0 readable pre-barrier
  G1_LD_A0(0, 0); G1_LD_B0(0, 0); G1_LD_A1(0, 0); G1_LD_B1(0, 0);
  WVM4;
  BAR;

  int par = 0;
#pragma unroll 1
  for (int t = 0; t < NT; ++t) {
    const bool nxt = (t + 1 < NT);
    const int kb = (t + 1) * 64;
    bf16x8 af[4], bg[2], bu[2];
    // ph0: kc0 mq0 (ready via prev ph3's vmcnt(4)+BAR)
    G1_RDB(par, 0); G1_RDA(par, 0, 0);
    if (nxt) G1_LD_A0(kb, par ^ 1);
    BAR; WAITL; G1_MFMA(0); BAR;
    // ph1: kc0 mq1; tail vmcnt makes kc1 ready across waves after BAR
    G1_RDA(par, 1, 0);
    if (nxt) { G1_LD_B0(kb, par ^ 1); WVM4; } else { WVM0; }
    BAR; WAITL; G1_MFMA(1); BAR;
    // ph2: kc1 mq0
    G1_RDB(par, 1); G1_RDA(par, 0, 1);
    if (nxt) G1_LD_A1(kb, par ^ 1);
    BAR; WAITL; G1_MFMA(0); BAR;
    // ph3: kc1 mq1; tail vmcnt makes next tile's kc0 ready after BAR
    G1_RDA(par, 1, 1);
    if (nxt) { G1_LD_B1(kb, par ^ 1); WVM4; }
    BAR; WAITL; G1_MFMA(1); BAR;
    par ^= 1;
  }
#undef G1_LD_A0
#undef G1_LD_B0
#undef G1_LD_A1
#undef G1_LD_B1
#undef G1_RDB
#undef G1_RDA
#undef G1_MFMA

#pragma unroll
  for (int mg = 0; mg < 8; mg++) {
    const int row0 = m0 + wm * 128 + mg * 16 + ((lane >> 4) << 2);
#pragma unroll
    for (int ni = 0; ni < 2; ni++) {
      const int c = hc0 + wn * 32 + ni * 16 + fm;
#pragma unroll
      for (int r = 0; r < 4; r++) {
        const float a = accg[mg][ni][r];
        const float b = accu[mg][ni][r];
        const float sv = a / (1.0f + __expf(-a));
        H[(size_t)(row0 + r) * (2 * H_DIM) + c] = (__bf16)(sv * b);
      }
    }
  }
}

// ---------------------------------------------------------------------------
// Unified GEMM2, race-free 4-phase/K-tile, 256x256 tile, gathered A.
// SWIZZLED LDS (R16/R18 gemm2 body, measured neutral-to-positive).
__global__ __launch_bounds__(512, 1) void gemm2_moe(
    const __bf16* __restrict__ Hb,   // [8192, 2048]
    const __bf16* __restrict__ W2,   // [9, 512, 1024]
    const float* __restrict__ comb,  // [8192, 8]
    const int* __restrict__ cnt,     // [8]
    const int* __restrict__ tok,     // [8, 8192]
    const int* __restrict__ off,     // [9] tile prefix (256-row tiles)
    const int* __restrict__ toff,    // [9] token prefix
    __bf16* __restrict__ Eo,         // [24576, 512]
    float* __restrict__ out,         // fallback only
    int compact)
{
  constexpr int K = H_DIM;    // 1024
  constexpr int NT = K / 64;  // 16 K-tiles
  __shared__ __bf16 As[8 * 4096];
  __shared__ __bf16 Bs[8 * 4096];
  __shared__ int tokLDS[256];

  const int g = blockIdx.x;
  const int T = off[8];
  int e, m0;
  if (g < T) {
    e = 0;
    while (e < 7 && g >= off[e + 1]) e++;
    m0 = (g - off[e]) * 256;
  } else if (g < T + 32) {
    e = 8;
    m0 = (g - T) * 256;
  } else {
    return;
  }
  const int cnt_e = (e == 8) ? S_TOT : cnt[e];
  const int n0 = blockIdx.y * 256;
  const __bf16* Bw = W2 + (size_t)e * C_DIM * H_DIM;
  const int abase = (e == 8) ? 0 : H_DIM;

  const int tid = threadIdx.x, wave = tid >> 6, lane = tid & 63;
  const int wm = wave >> 2, wn = wave & 3;
  const int fm = lane & 15, fq = (lane >> 4) * 8;
  const int fqs = fq ^ (((fm >> 1) & 3) << 3);              // read side
  const int srow = wave * 16 + (lane >> 2);
  const int scol = (((lane & 3) ^ ((lane >> 3) & 3)) * 8);  // source side
  const int woff = wave * 512;

  if (tid < 256) {
    const int r = m0 + tid;
    tokLDS[tid] = (e == 8) ? r : ((r < cnt_e) ? tok[e * S_TOT + r] : -1);
  }
  __syncthreads();   // tokLDS visible; vmcnt clean before pipelined loop

  int tk0 = tokLDS[srow];       if (tk0 < 0) tk0 = 0;
  int tk1 = tokLDS[128 + srow]; if (tk1 < 0) tk1 = 0;
  const __bf16* aR0 = Hb + abase + (size_t)tk0 * (2 * H_DIM) + scol;
  const __bf16* aR1 = Hb + abase + (size_t)tk1 * (2 * H_DIM) + scol;
  const __bf16* bR0 = Bw + (size_t)(n0 + srow) * K + scol;
  const __bf16* bR1 = Bw + (size_t)(n0 + 128 + srow) * K + scol;

  f32x4 acc[8][4] = {};

#define G2_LD_A0(kb, par) do {                                  \
    gload_lds16(aR0 + (kb), As + PNL(par, 0, 0) + woff);        \
    gload_lds16(aR1 + (kb), As + PNL(par, 1, 0) + woff); } while (0)
#define G2_LD_B0(kb, par) do {                                  \
    gload_lds16(bR0 + (kb), Bs + PNL(par, 0, 0) + woff);        \
    gload_lds16(bR1 + (kb), Bs + PNL(par, 1, 0) + woff); } while (0)
#define G2_LD_A1(kb, par) do {                                  \
    gload_lds16(aR0 + (kb) + 32, As + PNL(par, 0, 1) + woff);   \
    gload_lds16(aR1 + (kb) + 32, As + PNL(par, 1, 1) + woff); } while (0)
#define G2_LD_B1(kb, par) do {                                  \
    gload_lds16(bR0 + (kb) + 32, Bs + PNL(par, 0, 1) + woff);   \
    gload_lds16(bR1 + (kb) + 32, Bs + PNL(par, 1, 1) + woff); } while (0)

#define G2_RDB(par, kc) do {                                                   \
    _Pragma("unroll")                                                          \
    for (int ni = 0; ni < 4; ni++)                                             \
      bfr[ni] = *(const bf16x8*)&Bs[PNL(par, (wn >> 1), kc) +                  \
                  ((wn & 1) * 64 + ni * 16 + fm) * 32 + fqs];                  \
  } while (0)

#define G2_RDA(par, mq, kc) do {                                               \
    _Pragma("unroll")                                                          \
    for (int mi = 0; mi < 4; mi++)                                             \
      af[mi] = *(const bf16x8*)&As[PNL(par, wm, kc) +                          \
                                   ((mq) * 64 + mi * 16 + fm) * 32 + fqs];     \
  } while (0)

#define G2_MFMA(mq) do {                                                       \
    __builtin_amdgcn_s_setprio(1);                                             \
    _Pragma("unroll")                                                          \
    for (int mi = 0; mi < 4; mi++) {                                           \
      _Pragma("unroll")                                                        \
      for (int ni = 0; ni < 4; ni++)                                           \
        acc[(mq) * 4 + mi][ni] = __builtin_amdgcn_mfma_f32_16x16x32_bf16(      \
            af[mi], bfr[ni], acc[(mq) * 4 + mi][ni], 0, 0, 0);                 \
    }                                                                          \
    __builtin_amdgcn_s_setprio(0);                                             \
  } while (0)

  // prologue: tile 0 (kc order); vmcnt(4)+BAR => kc0 readable pre-barrier
  G2_LD_A0(0, 0); G2_LD_B0(0, 0); G2_LD_A1(0, 0); G2_LD_B1(0, 0);
  WVM4;
  BAR;

  int par = 0;
#pragma unroll 1
  for (int t = 0; t < NT; ++t) {
    const bool nxt = (t + 1 < NT);
    const int kb = (t + 1) * 64;
    bf16x8 af[4], bfr[4];
    // ph0: kc0 mq0
    G2_RDB(par, 0); G2_RDA(par, 0, 0);
    if (nxt) G2_LD_A0(kb, par ^ 1);
    BAR; WAITL; G2_MFMA(0); BAR;
    // ph1: kc0 mq1; tail vmcnt readies kc1
    G2_RDA(par, 1, 0);
    if (nxt) { G2_LD_B0(kb, par ^ 1); WVM4; } else { WVM0; }
    BAR; WAITL; G2_MFMA(1); BAR;
    // ph2: kc1 mq0
    G2_RDB(par, 1); G2_RDA(par, 0, 1);
    if (nxt) G2_LD_A1(kb, par ^ 1);
    BAR; WAITL; G2_MFMA(0); BAR;
    // ph3: kc1 mq1; tail vmcnt readies next kc0
    G2_RDA(par, 1, 1);
    if (nxt) { G2_LD_B1(kb, par ^ 1); WVM4; }
    BAR; WAITL; G2_MFMA(1); BAR;
    par ^= 1;
  }
#undef G2_LD_A0
#undef G2_LD_B0
#undef G2_LD_A1
#undef G2_LD_B1
#undef G2_RDB
#undef G2_RDA
#undef G2_MFMA

  const int toffE = (e < 8) ? toff[e] : 0;
#pragma unroll
  for (int mg = 0; mg < 8; mg++) {
    const int rbase = wm * 128 + mg * 16 + ((lane >> 4) << 2);
#pragma unroll
    for (int r = 0; r < 4; r++) {
      const int rowIdx = rbase + r;
      const int token = tokLDS[rowIdx];
      if (token < 0) continue;
      if (compact) {
        __bf16* dst;
        float scale;
        if (e == 8) {
          dst = &Eo[(size_t)(16384 + token) * C_DIM];
          scale = 1.0f;
        } else {
          dst = &Eo[(size_t)(toffE + m0 + rowIdx) * C_DIM];
          scale = comb[(size_t)token * 8 + e];
        }
#pragma unroll
        for (int ni = 0; ni < 4; ni++) {
          const int c = n0 + wn * 64 + ni * 16 + fm;
          dst[c] = (__bf16)(scale * acc[mg][ni][r]);
        }
      } else {
        const float scale = (e == 8) ? 1.0f : comb[(size_t)token * 8 + e];
        if (scale != 0.0f) {
#pragma unroll
          for (int ni = 0; ni < 4; ni++) {
            const int c = n0 + wn * 64 + ni * 16 + fm;
            atomicAdd(&out[(size_t)token * C_DIM + c], scale * acc[mg][ni][r]);
          }
        }
      }
    }
  }
}

// ---------------------------------------------------------------------------
__global__ __launch_bounds__(256) void bias_init(
    const int2* __restrict__ sm, const float* __restrict__ sob,
    const float* __restrict__ eob, float* __restrict__ out) {
  const int wave = threadIdx.x >> 6, lane = threadIdx.x & 63;
  const int s = blockIdx.x * 4 + wave;
  const int c0 = lane * 8;
  const int2 m = sm[s];
  const int e0 = m.x >> 16;
  const float4 za = *(const float4*)(sob + c0);
  const float4 zb = *(const float4*)(sob + c0 + 4);
  const float4 ea = *(const float4*)(eob + e0 * C_DIM + c0);
  const float4 eb2 = *(const float4*)(eob + e0 * C_DIM + c0 + 4);
  float accv[8] = {za.x + ea.x, za.y + ea.y, za.z + ea.z, za.w + ea.w,
                   zb.x + eb2.x, zb.y + eb2.y, zb.z + eb2.z, zb.w + eb2.w};
  if (m.y >= 0) {
    const int e1 = m.y >> 16;
    const float4 fa = *(const float4*)(eob + e1 * C_DIM + c0);
    const float4 fb = *(const float4*)(eob + e1 * C_DIM + c0 + 4);
    accv[0] += fa.x; accv[1] += fa.y; accv[2] += fa.z; accv[3] += fa.w;
    accv[4] += fb.x; accv[5] += fb.y; accv[6] += fb.z; accv[7] += fb.w;
  }
  float* dst = out + (size_t)s * C_DIM + c0;
  *(float4*)(dst)     = make_float4(accv[0], accv[1], accv[2], accv[3]);
  *(float4*)(dst + 4) = make_float4(accv[4], accv[5], accv[6], accv[7]);
}

// ---------------------------------------------------------------------------
__global__ __launch_bounds__(256) void combine(
    const __bf16* __restrict__ Eo, const int2* __restrict__ sm,
    const int* __restrict__ toff, const float* __restrict__ sob,
    const float* __restrict__ eob, float* __restrict__ out) {
  const int wave = threadIdx.x >> 6, lane = threadIdx.x & 63;
  const int s = blockIdx.x * 4 + wave;
  const int c0 = lane * 8;
  const int2 m = sm[s];
  const int e0 = m.x >> 16, p0 = m.x & 0xffff;

  const bf16x8 vs = *(const bf16x8*)(Eo + (size_t)(16384 + s) * C_DIM + c0);
  const bf16x8 v0 = *(const bf16x8*)(Eo + (size_t)(toff[e0] + p0) * C_DIM + c0);
  const float4 za = *(const float4*)(sob + c0);
  const float4 zb = *(const float4*)(sob + c0 + 4);
  const float4 ea = *(const float4*)(eob + e0 * C_DIM + c0);
  const float4 eb2 = *(const float4*)(eob + e0 * C_DIM + c0 + 4);
  float accv[8] = {za.x + ea.x, za.y + ea.y, za.z + ea.z, za.w + ea.w,
                   zb.x + eb2.x, zb.y + eb2.y, zb.z + eb2.z, zb.w + eb2.w};
#pragma unroll
  for (int j = 0; j < 8; j++) accv[j] += (float)vs[j] + (float)v0[j];
  if (m.y >= 0) {
    const int e1 = m.y >> 16, p1 = m.y & 0xffff;
    const bf16x8 v1 = *(const bf16x8*)(Eo + (size_t)(toff[e1] + p1) * C_DIM + c0);
    const float4 fa = *(const float4*)(eob + e1 * C_DIM + c0);
    const float4 fb = *(const float4*)(eob + e1 * C_DIM + c0 + 4);
    const float b1[8] = {fa.x, fa.y, fa.z, fa.w, fb.x, fb.y, fb.z, fb.w};
#pragma unroll
    for (int j = 0; j < 8; j++) accv[j] += (float)v1[j] + b1[j];
  }
  float* dst = out + (size_t)s * C_DIM + c0;
  *(float4*)(dst)     = make_float4(accv[0], accv[1], accv[2], accv[3]);
  *(float4*)(dst + 4) = make_float4(accv[4], accv[5], accv[6], accv[7]);
}

// ---------------------------------------------------------------------------
extern "C" void kernel_launch(void* const* d_in, const int* in_sizes, int n_in,
                              void* d_out, int out_size, void* d_ws, size_t ws_size,
                              hipStream_t stream) {
  const float* x    = (const float*)d_in[0];
  const float* lns  = (const float*)d_in[1];
  const float* lnbi = (const float*)d_in[2];
  const float* siw  = (const float*)d_in[3];
  const float* sow  = (const float*)d_in[4];
  const float* sob  = (const float*)d_in[5];
  const float* eiw  = (const float*)d_in[6];
  const float* eow  = (const float*)d_in[7];
  const float* eob  = (const float*)d_in[8];
  const float* ggw  = (const float*)d_in[9];
  const float* egw  = (const float*)d_in[10];
  const float* gb   = (const float*)d_in[11];
  const float* eb   = (const float*)d_in[12];
  float* out = (float*)d_out;

  char* ws = (char*)d_ws;
  __bf16* w1   = (__bf16*)(ws);                 //  4,194,304  [4096,512]
  __bf16* w2   = (__bf16*)(ws + 4194304);       //  9,437,184  [9,512,1024]
  __bf16* lnb  = (__bf16*)(ws + 13631488);      //  8,388,608  [8192,512]
  __bf16* Hbuf = (__bf16*)(ws + 22020096);      // 33,554,432  [8192,2048]
  float*  comb = (float*)(ws + 55574528);       //    262,144  [8192,8]
  int*    tok  = (int*)(ws + 55836672);         //    262,144  [8,8192]
  int2*   sm   = (int2*)(ws + 56098816);        //     65,536  [8192]
  int*    cnt  = (int*)(ws + 56164352);         //         32  [8]
  int*    done = (int*)(ws + 56164384);         //          4  (cnt+8)
  int*    off  = (int*)(ws + 56164416);         //         36  [9]
  int*    toff = (int*)(ws + 56164452);         //         36  [9]
  __bf16* Eo   = (__bf16*)(ws + 56164512);      // 25,165,824  [24576,512]
  const size_t NEED = 81330336;
  const int compact = (ws_size >= NEED) ? 1 : 0;

  // A) fused LN+gating (blocks 0..2047) + weight cvt (blocks 2048..8703);
  //    block 0 zeroes cnt[8]+done.
  ln_gate_cvt<<<2048 + 6656, 256, 0, stream>>>(
      x, lns, lnbi, ggw, egw, gb, eb, lnb, comb, cnt,
      siw, eiw, eow, sow, w1, w2);

  // B) GEMM1 + SwiGLU; blocks (y==0, x<16) also build expert lists/prefixes.
  gemm1_swiglu<<<dim3(S_TOT / 256, 2 * H_DIM / 128), 512, 0, stream>>>(
      lnb, w1, Hbuf, comb, cnt, tok, sm, done, off, toff);

  if (!compact)
    bias_init<<<S_TOT / 4, 256, 0, stream>>>(sm, sob, eob, out);

  // C) compacted GEMM2
  gemm2_moe<<<dim3(MAX_ET2 + 32, C_DIM / 256), 512, 0, stream>>>(
      Hbuf, w2, comb, cnt, tok, off, toff, Eo, out, compact);

  // D) per-token combine
  if (compact)
    combine<<<S_TOT / 4, 256, 0, stream>>>(Eo, sm, toff, sob, eob, out);
}